// Round 9
// baseline (256.252 us; speedup 1.0000x reference)
//
#include <hip/hip_runtime.h>
#include <math.h>
#include <limits.h>

#define NPTS    50000
#define NCHUNK  16
#define CHUNK   3328             // 13 groups of 256
#define NGROUP  13
#define NPAD    (NCHUNK * CHUNK) // 53248
#define NQ      4000
#define KNN     4
#define QG      8                // queries per wave
#define NWAVE   8000             // (NQ/QG) * NCHUNK = 500*16
#define NBLK    (NWAVE / 4)      // 2000
#define CAP     12               // per-(query,chunk) pool (u16 index-only)
#define BIGF    3.0e38f

// workspace layout (bytes)
#define PK_OFF  0
#define CNT_OFF (NPAD * 16)                          // 851968
#define IL_OFF  (CNT_OFF + NQ * NCHUNK * 4)          // 1107968
#define WS_NEED (IL_OFF + NQ * NCHUNK * CAP * 2)     // 2643968 (< 2887296 proven)

// EXACT reference arithmetic: packed P = {x, y, z, p2s}
// dot = (q0*x + q1*y) + q2*z ; d2 = (q2s + p2s) - 2*dot   (no FMA contraction)
__device__ __forceinline__ float d2_of(float qx, float qy, float qz, float qs, float4 P) {
    float dot = __fadd_rn(__fadd_rn(__fmul_rn(qx, P.x), __fmul_rn(qy, P.y)),
                          __fmul_rn(qz, P.z));
    return __fsub_rn(__fadd_rn(qs, P.w), __fmul_rn(2.0f, dot));
}

// lex (dist, idx) insert into sorted ascending 4-list
__device__ __forceinline__ void lex_insert(float (&bd)[KNN], int (&bi)[KNN],
                                           float dist, int idx) {
    if (dist < bd[KNN - 1] || (dist == bd[KNN - 1] && idx < bi[KNN - 1])) {
        bd[KNN - 1] = dist; bi[KNN - 1] = idx;
#pragma unroll
        for (int k = KNN - 1; k > 0; --k) {
            bool sw = (bd[k] < bd[k - 1]) || (bd[k] == bd[k - 1] && bi[k] < bi[k - 1]);
            if (sw) {
                float td = bd[k]; bd[k] = bd[k - 1]; bd[k - 1] = td;
                int   ti = bi[k]; bi[k] = bi[k - 1]; bi[k - 1] = ti;
            }
        }
    }
}

// butterfly merge of per-lane sorted 4-lists -> wave-global lex top-4 (all lanes)
__device__ __forceinline__ void wave_merge4(float (&bd)[KNN], int (&bi)[KNN]) {
    for (int m = 1; m < 64; m <<= 1) {
        float od[KNN]; int oi[KNN];
#pragma unroll
        for (int j = 0; j < KNN; ++j) {
            od[j] = __shfl_xor(bd[j], m, 64);
            oi[j] = __shfl_xor(bi[j], m, 64);
        }
        float md[KNN]; int mi[KNN]; int a = 0, b = 0;
#pragma unroll
        for (int j = 0; j < KNN; ++j) {
            const bool takeA = (bd[a] < od[b]) || (bd[a] == od[b] && bi[a] <= oi[b]);
            if (takeA) { md[j] = bd[a]; mi[j] = bi[a]; ++a; }
            else       { md[j] = od[b]; mi[j] = oi[b]; ++b; }
        }
#pragma unroll
        for (int j = 0; j < KNN; ++j) { bd[j] = md[j]; bi[j] = mi[j]; }
    }
}

// ---------------- pack: [N,3] -> {x,y,z,p2s}, sentinel pad ------------------
__global__ __launch_bounds__(256) void pack_kernel(const float* __restrict__ pts,
                                                   float4* __restrict__ packed) {
    int t = blockIdx.x * 256 + threadIdx.x;   // grid = NPAD/256 = 208, covers exactly
    if (t < NPTS) {
        float x = pts[3 * t], y = pts[3 * t + 1], z = pts[3 * t + 2];
        float s = __fadd_rn(__fadd_rn(__fmul_rn(x, x), __fmul_rn(y, y)),
                            __fmul_rn(z, z));
        packed[t] = make_float4(x, y, z, s);
    } else {
        packed[t] = make_float4(0.f, 0.f, 0.f, BIGF);   // never passes tau filter
    }
}

// ---------------- main: pass A (min -> tau2 per query), pass B (u16 push) ---
// Block b: chunk = b & 15 (all waves share one 53KB chunk; same-chunk blocks
// land on one XCD under round-robin dispatch), 4 query-groups per block.
__global__ __launch_bounds__(256, 8) void knn_main(const float4* __restrict__ pk,
                                                   const float* __restrict__ queries,
                                                   int* __restrict__ cnt,
                                                   unsigned short* __restrict__ il) {
    const int lane  = threadIdx.x & 63;
    const int widx  = threadIdx.x >> 6;
    const int chunk = blockIdx.x & 15;
    const int qg    = (blockIdx.x >> 4) * 4 + widx;   // [0, 500)
    const int qbase = qg * QG;

    float qx[QG], qy[QG], qz[QG], qs[QG];
#pragma unroll
    for (int j = 0; j < QG; ++j) {
        float a = queries[(qbase + j) * 3 + 0];
        float b = queries[(qbase + j) * 3 + 1];
        float c = queries[(qbase + j) * 3 + 2];
        qx[j] = a; qy[j] = b; qz[j] = c;
        qs[j] = __fadd_rn(__fadd_rn(__fmul_rn(a, a), __fmul_rn(b, b)),
                          __fmul_rn(c, c));
    }

    // ---- pass A: per-lane min of d2 per query (read-then-advance) ----
    const float4* p = pk + chunk * CHUNK + lane;
    float mn[QG];
#pragma unroll
    for (int j = 0; j < QG; ++j) mn[j] = BIGF;

#pragma unroll 1
    for (int g = 0; g < NGROUP; ++g) {
        float4 a = p[0], b = p[64], c = p[128], d = p[192];
        p += 256;
#pragma unroll
        for (int j = 0; j < QG; ++j) {
            float da = d2_of(qx[j], qy[j], qz[j], qs[j], a);
            float db = d2_of(qx[j], qy[j], qz[j], qs[j], b);
            float dc = d2_of(qx[j], qy[j], qz[j], qs[j], c);
            float dd = d2_of(qx[j], qy[j], qz[j], qs[j], d);
            mn[j] = fminf(mn[j], fminf(fminf(da, db), fminf(dc, dd)));
        }
    }

    // ---- tau2 per query: 4th-distinct-smallest of 64 lane mins + slack ----
    float tau2[QG];
#pragma unroll
    for (int j = 0; j < QG; ++j) {
        float v = mn[j], tau = mn[j];
#pragma unroll
        for (int r = 0; r < 4; ++r) {
            float t = v;
#pragma unroll
            for (int s = 1; s < 64; s <<= 1) t = fminf(t, __shfl_xor(t, s, 64));
            tau = t;
            v = (v == t) ? BIGF : v;
        }
        float tdist = __fsqrt_rn(fmaxf(tau, 0.f));
        float t2 = __fmul_rn(__fmul_rn(tdist, tdist), 1.000002f);
        tau2[j] = (t2 < tau) ? tau : t2;
    }

    // ---- pass B: rescan, rare atomic pushes (u16 index only) ----
    p = pk + chunk * CHUNK + lane;
    int pb = chunk * CHUNK + lane;
#pragma unroll 1
    for (int g = 0; g < NGROUP; ++g) {
        float4 a = p[0], b = p[64], c = p[128], d = p[192];
        p += 256;
#pragma unroll
        for (int j = 0; j < QG; ++j) {
            float da = d2_of(qx[j], qy[j], qz[j], qs[j], a);
            float db = d2_of(qx[j], qy[j], qz[j], qs[j], b);
            float dc = d2_of(qx[j], qy[j], qz[j], qs[j], c);
            float dd = d2_of(qx[j], qy[j], qz[j], qs[j], d);
            float t4 = fminf(fminf(da, db), fminf(dc, dd));
            if (t4 <= tau2[j]) {
                const int pool = (qbase + j) * NCHUNK + chunk;
                if (da <= tau2[j]) { int pos = atomicAdd(&cnt[pool], 1); if (pos >= 0 && pos < CAP) il[pool*CAP+pos] = (unsigned short)pb; }
                if (db <= tau2[j]) { int pos = atomicAdd(&cnt[pool], 1); if (pos >= 0 && pos < CAP) il[pool*CAP+pos] = (unsigned short)(pb + 64); }
                if (dc <= tau2[j]) { int pos = atomicAdd(&cnt[pool], 1); if (pos >= 0 && pos < CAP) il[pool*CAP+pos] = (unsigned short)(pb + 128); }
                if (dd <= tau2[j]) { int pos = atomicAdd(&cnt[pool], 1); if (pos >= 0 && pos < CAP) il[pool*CAP+pos] = (unsigned short)(pb + 192); }
            }
        }
        pb += 256;
    }
}

// ---------------- final: one wave per query, 192 slots, butterfly merge -----
__global__ __launch_bounds__(256) void knn_final(const int* __restrict__ cnt,
                                                 const unsigned short* __restrict__ il,
                                                 const float* __restrict__ points,
                                                 const float* __restrict__ queries,
                                                 float* __restrict__ out) {
    const int q    = blockIdx.x * 4 + (threadIdx.x >> 6);  // [0, 4000)
    const int lane = threadIdx.x & 63;

    const float q0 = queries[q*3+0], q1 = queries[q*3+1], q2v = queries[q*3+2];
    const float q2s = __fadd_rn(__fadd_rn(__fmul_rn(q0,q0), __fmul_rn(q1,q1)),
                                __fmul_rn(q2v,q2v));

    float bd[KNN]; int bi[KNN];
#pragma unroll
    for (int k = 0; k < KNN; ++k) { bd[k] = INFINITY; bi[k] = INT_MAX; }

    // per-lane slots lane, lane+64, lane+128 over the 16 pools x CAP=12
    int sc[3], sj[3], sn[3];
    bool o = false;
#pragma unroll
    for (int t = 0; t < 3; ++t) {
        int s = lane + t * 64;
        int c = s / CAP;
        sc[t] = c; sj[t] = s - c * CAP;
        sn[t] = cnt[q * NCHUNK + c];
        o = o || (sn[t] > CAP);
    }

    if (!__any(o)) {
#pragma unroll
        for (int t = 0; t < 3; ++t) {
            if (sj[t] < sn[t]) {
                int idx = (int)il[(q * NCHUNK + sc[t]) * CAP + sj[t]];
                float x = points[idx*3], y = points[idx*3+1], z = points[idx*3+2];
                float p2s = __fadd_rn(__fadd_rn(__fmul_rn(x,x), __fmul_rn(y,y)), __fmul_rn(z,z));
                float dot = __fadd_rn(__fadd_rn(__fmul_rn(q0,x), __fmul_rn(q1,y)), __fmul_rn(q2v,z));
                float d2  = __fsub_rn(__fadd_rn(q2s, p2s), __fmul_rn(2.0f, dot));
                lex_insert(bd, bi, __fsqrt_rn(fmaxf(d2, 0.f)), idx);
            }
        }
    } else {
        // overflow repair (rare): wave-parallel brute force, exact arithmetic
        for (int p = lane; p < NPTS; p += 64) {
            float x = points[p*3], y = points[p*3+1], z = points[p*3+2];
            float p2s = __fadd_rn(__fadd_rn(__fmul_rn(x,x), __fmul_rn(y,y)), __fmul_rn(z,z));
            float dot = __fadd_rn(__fadd_rn(__fmul_rn(q0,x), __fmul_rn(q1,y)), __fmul_rn(q2v,z));
            float d2  = __fsub_rn(__fadd_rn(q2s, p2s), __fmul_rn(2.0f, dot));
            lex_insert(bd, bi, __fsqrt_rn(fmaxf(d2, 0.f)), p);
        }
    }

    wave_merge4(bd, bi);

    if (lane == 0) {
#pragma unroll
        for (int k = 0; k < KNN; ++k) {
            out[q * KNN + k]            = bd[k];
            out[NQ * KNN + q * KNN + k] = (float)bi[k];
        }
    }
}

// ---------------- fallback (round-1 kernel, passed) if ws too small ---------
__global__ __launch_bounds__(256) void knn_fallback(const float* __restrict__ points,
                                                    const float* __restrict__ queries,
                                                    float* __restrict__ out) {
    const int gtid = blockIdx.x * blockDim.x + threadIdx.x;
    const int wave = gtid >> 6;
    const int lane = threadIdx.x & 63;
    if (wave >= NQ) return;
    const float q0 = queries[wave*3+0], q1 = queries[wave*3+1], q2v = queries[wave*3+2];
    const float q2s = __fadd_rn(__fadd_rn(__fmul_rn(q0,q0), __fmul_rn(q1,q1)), __fmul_rn(q2v,q2v));
    float bd[KNN]; int bi[KNN];
#pragma unroll
    for (int j = 0; j < KNN; ++j) { bd[j] = INFINITY; bi[j] = INT_MAX; }
    for (int p = lane; p < NPTS; p += 64) {
        float x = points[p*3], y = points[p*3+1], z = points[p*3+2];
        float p2s = __fadd_rn(__fadd_rn(__fmul_rn(x,x), __fmul_rn(y,y)), __fmul_rn(z,z));
        float dot = __fadd_rn(__fadd_rn(__fmul_rn(q0,x), __fmul_rn(q1,y)), __fmul_rn(q2v,z));
        float d2 = __fsub_rn(__fadd_rn(q2s, p2s), __fmul_rn(2.0f, dot));
        lex_insert(bd, bi, __fsqrt_rn(fmaxf(d2, 0.f)), p);
    }
    wave_merge4(bd, bi);
    if (lane == 0) {
#pragma unroll
        for (int j = 0; j < KNN; ++j) {
            out[wave*KNN+j] = bd[j];
            out[NQ*KNN + wave*KNN + j] = (float)bi[j];
        }
    }
}

extern "C" void kernel_launch(void* const* d_in, const int* in_sizes, int n_in,
                              void* d_out, int out_size, void* d_ws, size_t ws_size,
                              hipStream_t stream) {
    const float* points  = (const float*)d_in[0];
    const float* queries = (const float*)d_in[1];
    float* out = (float*)d_out;

    if (ws_size < (size_t)WS_NEED) {
        knn_fallback<<<(NQ * 64 + 255) / 256, 256, 0, stream>>>(points, queries, out);
        return;
    }

    char* ws = (char*)d_ws;
    float4*         packed = (float4*)(ws + PK_OFF);
    int*            cnt    = (int*)(ws + CNT_OFF);
    unsigned short* il     = (unsigned short*)(ws + IL_OFF);

    pack_kernel<<<NPAD / 256, 256, 0, stream>>>(points, packed);
    (void)hipMemsetAsync(cnt, 0, NQ * NCHUNK * sizeof(int), stream);
    knn_main<<<NBLK, 256, 0, stream>>>(packed, queries, cnt, il);
    knn_final<<<NQ / 4, 256, 0, stream>>>(cnt, il, points, queries, out);
}

// Round 10
// 98.658 us; speedup vs baseline: 2.5974x; 2.5974x over previous
//
#include <hip/hip_runtime.h>
#include <math.h>
#include <limits.h>

#define NPTS    50000
#define NCHUNK  16
#define CHUNK   3328             // 13 groups of 256
#define NGROUP  13
#define NPAD    (NCHUNK * CHUNK) // 53248
#define NQ      4000
#define KNN     4
#define QG      8                // queries per wave
#define NWAVE   8000             // (NQ/QG) * NCHUNK = 500*16
#define NBLK    (NWAVE / 4)      // 2000
#define CAP     12               // per-(query,chunk) pool (u16 index-only)
#define BIGF    3.0e38f

// workspace layout (bytes)
#define PK_OFF  0
#define CNT_OFF (NPAD * 16)                          // 851968
#define IL_OFF  (CNT_OFF + NQ * NCHUNK * 4)          // 1107968
#define WS_NEED (IL_OFF + NQ * NCHUNK * CAP * 2)     // 2643968 (< 2887296 proven)

// lex (dist, idx) insert into sorted ascending 4-list
__device__ __forceinline__ void lex_insert(float (&bd)[KNN], int (&bi)[KNN],
                                           float dist, int idx) {
    if (dist < bd[KNN - 1] || (dist == bd[KNN - 1] && idx < bi[KNN - 1])) {
        bd[KNN - 1] = dist; bi[KNN - 1] = idx;
#pragma unroll
        for (int k = KNN - 1; k > 0; --k) {
            bool sw = (bd[k] < bd[k - 1]) || (bd[k] == bd[k - 1] && bi[k] < bi[k - 1]);
            if (sw) {
                float td = bd[k]; bd[k] = bd[k - 1]; bd[k - 1] = td;
                int   ti = bi[k]; bi[k] = bi[k - 1]; bi[k - 1] = ti;
            }
        }
    }
}

// butterfly merge of per-lane sorted 4-lists -> wave-global lex top-4 (all lanes)
__device__ __forceinline__ void wave_merge4(float (&bd)[KNN], int (&bi)[KNN]) {
    for (int m = 1; m < 64; m <<= 1) {
        float od[KNN]; int oi[KNN];
#pragma unroll
        for (int j = 0; j < KNN; ++j) {
            od[j] = __shfl_xor(bd[j], m, 64);
            oi[j] = __shfl_xor(bi[j], m, 64);
        }
        float md[KNN]; int mi[KNN]; int a = 0, b = 0;
#pragma unroll
        for (int j = 0; j < KNN; ++j) {
            const bool takeA = (bd[a] < od[b]) || (bd[a] == od[b] && bi[a] <= oi[b]);
            if (takeA) { md[j] = bd[a]; mi[j] = bi[a]; ++a; }
            else       { md[j] = od[b]; mi[j] = oi[b]; ++b; }
        }
#pragma unroll
        for (int j = 0; j < KNN; ++j) { bd[j] = md[j]; bi[j] = mi[j]; }
    }
}

// ---------------- pack: [N,3] -> {x,y,z,p2s}, sentinel pad ------------------
__global__ __launch_bounds__(256) void pack_kernel(const float* __restrict__ pts,
                                                   float4* __restrict__ packed) {
    int t = blockIdx.x * 256 + threadIdx.x;   // grid = NPAD/256 = 208, covers exactly
    if (t < NPTS) {
        float x = pts[3 * t], y = pts[3 * t + 1], z = pts[3 * t + 2];
        float s = __fadd_rn(__fadd_rn(__fmul_rn(x, x), __fmul_rn(y, y)),
                            __fmul_rn(z, z));
        packed[t] = make_float4(x, y, z, s);
    } else {
        packed[t] = make_float4(0.f, 0.f, 0.f, BIGF);   // never passes tau filter
    }
}

// fast filter distance: 4 ops. d2' = ((qs + mx*x + my*y + mz*z) + p2s), m=-2q.
// |d2' - d2_exact| <= ~5e-6 absolute; absorbed by tau2 margin below.
__device__ __forceinline__ float d2f(float mx, float my, float mz, float qs, float4 P) {
    float t = fmaf(mx, P.x, qs);
    t = fmaf(my, P.y, t);
    t = fmaf(mz, P.z, t);
    return t + P.w;
}

// ---------------- main: pass A (min -> tau2 per query), pass B (u16 push) ---
// Block b: chunk = b & 15 (4 waves share one 53KB chunk), 4 query-groups/block.
__global__ __launch_bounds__(256) void knn_main(const float4* __restrict__ pk,
                                                const float* __restrict__ queries,
                                                int* __restrict__ cnt,
                                                unsigned short* __restrict__ il) {
    const int lane  = threadIdx.x & 63;
    const int widx  = threadIdx.x >> 6;
    const int chunk = blockIdx.x & 15;
    const int qg    = (blockIdx.x >> 4) * 4 + widx;   // [0, 500)
    const int qbase = qg * QG;

    float mx[QG], my[QG], mz[QG], qs[QG];
#pragma unroll
    for (int j = 0; j < QG; ++j) {
        float a = queries[(qbase + j) * 3 + 0];
        float b = queries[(qbase + j) * 3 + 1];
        float c = queries[(qbase + j) * 3 + 2];
        mx[j] = __fmul_rn(-2.f, a);
        my[j] = __fmul_rn(-2.f, b);
        mz[j] = __fmul_rn(-2.f, c);
        qs[j] = __fadd_rn(__fadd_rn(__fmul_rn(a, a), __fmul_rn(b, b)),
                          __fmul_rn(c, c));
    }

    // ---- pass A: per-lane min of d2' per query (read-then-advance) ----
    const float4* p = pk + chunk * CHUNK + lane;
    float mn[QG];
#pragma unroll
    for (int j = 0; j < QG; ++j) mn[j] = BIGF;

#pragma unroll 1
    for (int g = 0; g < NGROUP; ++g) {
        float4 a = p[0], b = p[64], c = p[128], d = p[192];
        p += 256;
#pragma unroll
        for (int j = 0; j < QG; ++j) {
            float da = d2f(mx[j], my[j], mz[j], qs[j], a);
            float db = d2f(mx[j], my[j], mz[j], qs[j], b);
            float dc = d2f(mx[j], my[j], mz[j], qs[j], c);
            float dd = d2f(mx[j], my[j], mz[j], qs[j], d);
            mn[j] = fminf(mn[j], fminf(fminf(da, db), fminf(dc, dd)));
        }
    }

    // ---- tau2: 4th-distinct-smallest of 64 lane mins + abs/rel margin ----
    // margin covers contracted-vs-exact divergence (<=~5e-6 abs each side) and
    // the sqrt-rounding tie window; over-capture is harmless (final is exact).
    float tau2[QG];
#pragma unroll
    for (int j = 0; j < QG; ++j) {
        float v = mn[j], tau = mn[j];
#pragma unroll
        for (int r = 0; r < 4; ++r) {
            float t = v;
#pragma unroll
            for (int s = 1; s < 64; s <<= 1) t = fminf(t, __shfl_xor(t, s, 64));
            tau = t;
            v = (v == t) ? BIGF : v;
        }
        tau2[j] = fmaf(tau, 1.00001f, 1e-4f);
    }

    // ---- pass B: rescan, rare atomic pushes (u16 index only) ----
    p = pk + chunk * CHUNK + lane;
    int pb = chunk * CHUNK + lane;
#pragma unroll 1
    for (int g = 0; g < NGROUP; ++g) {
        float4 a = p[0], b = p[64], c = p[128], d = p[192];
        p += 256;
#pragma unroll
        for (int j = 0; j < QG; ++j) {
            float da = d2f(mx[j], my[j], mz[j], qs[j], a);
            float db = d2f(mx[j], my[j], mz[j], qs[j], b);
            float dc = d2f(mx[j], my[j], mz[j], qs[j], c);
            float dd = d2f(mx[j], my[j], mz[j], qs[j], d);
            float t4 = fminf(fminf(da, db), fminf(dc, dd));
            if (t4 <= tau2[j]) {
                const int pool = (qbase + j) * NCHUNK + chunk;
                if (da <= tau2[j]) { int pos = atomicAdd(&cnt[pool], 1); if (pos >= 0 && pos < CAP) il[pool*CAP+pos] = (unsigned short)pb; }
                if (db <= tau2[j]) { int pos = atomicAdd(&cnt[pool], 1); if (pos >= 0 && pos < CAP) il[pool*CAP+pos] = (unsigned short)(pb + 64); }
                if (dc <= tau2[j]) { int pos = atomicAdd(&cnt[pool], 1); if (pos >= 0 && pos < CAP) il[pool*CAP+pos] = (unsigned short)(pb + 128); }
                if (dd <= tau2[j]) { int pos = atomicAdd(&cnt[pool], 1); if (pos >= 0 && pos < CAP) il[pool*CAP+pos] = (unsigned short)(pb + 192); }
            }
        }
        pb += 256;
    }
}

// ---------------- final: one wave per query, 192 slots, EXACT arithmetic ----
__global__ __launch_bounds__(256) void knn_final(const int* __restrict__ cnt,
                                                 const unsigned short* __restrict__ il,
                                                 const float* __restrict__ points,
                                                 const float* __restrict__ queries,
                                                 float* __restrict__ out) {
    const int q    = blockIdx.x * 4 + (threadIdx.x >> 6);  // [0, 4000)
    const int lane = threadIdx.x & 63;

    const float q0 = queries[q*3+0], q1 = queries[q*3+1], q2v = queries[q*3+2];
    const float q2s = __fadd_rn(__fadd_rn(__fmul_rn(q0,q0), __fmul_rn(q1,q1)),
                                __fmul_rn(q2v,q2v));

    float bd[KNN]; int bi[KNN];
#pragma unroll
    for (int k = 0; k < KNN; ++k) { bd[k] = INFINITY; bi[k] = INT_MAX; }

    // per-lane slots lane, lane+64, lane+128 over the 16 pools x CAP=12
    int sc[3], sj[3], sn[3];
    bool o = false;
#pragma unroll
    for (int t = 0; t < 3; ++t) {
        int s = lane + t * 64;
        int c = s / CAP;
        sc[t] = c; sj[t] = s - c * CAP;
        sn[t] = cnt[q * NCHUNK + c];
        o = o || (sn[t] > CAP);
    }

    if (!__any(o)) {
#pragma unroll
        for (int t = 0; t < 3; ++t) {
            if (sj[t] < sn[t]) {
                int idx = (int)il[(q * NCHUNK + sc[t]) * CAP + sj[t]];
                float x = points[idx*3], y = points[idx*3+1], z = points[idx*3+2];
                float p2s = __fadd_rn(__fadd_rn(__fmul_rn(x,x), __fmul_rn(y,y)), __fmul_rn(z,z));
                float dot = __fadd_rn(__fadd_rn(__fmul_rn(q0,x), __fmul_rn(q1,y)), __fmul_rn(q2v,z));
                float d2  = __fsub_rn(__fadd_rn(q2s, p2s), __fmul_rn(2.0f, dot));
                lex_insert(bd, bi, __fsqrt_rn(fmaxf(d2, 0.f)), idx);
            }
        }
    } else {
        // overflow repair (rare): wave-parallel brute force, exact arithmetic
        for (int p = lane; p < NPTS; p += 64) {
            float x = points[p*3], y = points[p*3+1], z = points[p*3+2];
            float p2s = __fadd_rn(__fadd_rn(__fmul_rn(x,x), __fmul_rn(y,y)), __fmul_rn(z,z));
            float dot = __fadd_rn(__fadd_rn(__fmul_rn(q0,x), __fmul_rn(q1,y)), __fmul_rn(q2v,z));
            float d2  = __fsub_rn(__fadd_rn(q2s, p2s), __fmul_rn(2.0f, dot));
            lex_insert(bd, bi, __fsqrt_rn(fmaxf(d2, 0.f)), p);
        }
    }

    wave_merge4(bd, bi);

    if (lane == 0) {
#pragma unroll
        for (int k = 0; k < KNN; ++k) {
            out[q * KNN + k]            = bd[k];
            out[NQ * KNN + q * KNN + k] = (float)bi[k];
        }
    }
}

// ---------------- fallback (round-1 kernel, passed) if ws too small ---------
__global__ __launch_bounds__(256) void knn_fallback(const float* __restrict__ points,
                                                    const float* __restrict__ queries,
                                                    float* __restrict__ out) {
    const int gtid = blockIdx.x * blockDim.x + threadIdx.x;
    const int wave = gtid >> 6;
    const int lane = threadIdx.x & 63;
    if (wave >= NQ) return;
    const float q0 = queries[wave*3+0], q1 = queries[wave*3+1], q2v = queries[wave*3+2];
    const float q2s = __fadd_rn(__fadd_rn(__fmul_rn(q0,q0), __fmul_rn(q1,q1)), __fmul_rn(q2v,q2v));
    float bd[KNN]; int bi[KNN];
#pragma unroll
    for (int j = 0; j < KNN; ++j) { bd[j] = INFINITY; bi[j] = INT_MAX; }
    for (int p = lane; p < NPTS; p += 64) {
        float x = points[p*3], y = points[p*3+1], z = points[p*3+2];
        float p2s = __fadd_rn(__fadd_rn(__fmul_rn(x,x), __fmul_rn(y,y)), __fmul_rn(z,z));
        float dot = __fadd_rn(__fadd_rn(__fmul_rn(q0,x), __fmul_rn(q1,y)), __fmul_rn(q2v,z));
        float d2 = __fsub_rn(__fadd_rn(q2s, p2s), __fmul_rn(2.0f, dot));
        lex_insert(bd, bi, __fsqrt_rn(fmaxf(d2, 0.f)), p);
    }
    wave_merge4(bd, bi);
    if (lane == 0) {
#pragma unroll
        for (int j = 0; j < KNN; ++j) {
            out[wave*KNN+j] = bd[j];
            out[NQ*KNN + wave*KNN + j] = (float)bi[j];
        }
    }
}

extern "C" void kernel_launch(void* const* d_in, const int* in_sizes, int n_in,
                              void* d_out, int out_size, void* d_ws, size_t ws_size,
                              hipStream_t stream) {
    const float* points  = (const float*)d_in[0];
    const float* queries = (const float*)d_in[1];
    float* out = (float*)d_out;

    if (ws_size < (size_t)WS_NEED) {
        knn_fallback<<<(NQ * 64 + 255) / 256, 256, 0, stream>>>(points, queries, out);
        return;
    }

    char* ws = (char*)d_ws;
    float4*         packed = (float4*)(ws + PK_OFF);
    int*            cnt    = (int*)(ws + CNT_OFF);
    unsigned short* il     = (unsigned short*)(ws + IL_OFF);

    pack_kernel<<<NPAD / 256, 256, 0, stream>>>(points, packed);
    (void)hipMemsetAsync(cnt, 0, NQ * NCHUNK * sizeof(int), stream);
    knn_main<<<NBLK, 256, 0, stream>>>(packed, queries, cnt, il);
    knn_final<<<NQ / 4, 256, 0, stream>>>(cnt, il, points, queries, out);
}